// Round 2
// baseline (196.621 us; speedup 1.0000x reference)
//
#include <hip/hip_runtime.h>
#include <math.h>

// MoogVCF RF cell, fully fused single kernel.
//
// Algebra: with k=1/SR, w=2*pi*gf*1000, g=k*w/2:
//   Mlhs = I - (k/2)A*alpha  = [[d,0,0,e],[-a,d,0,0],[0,-a,d,0],[0,0,-a,d]]
//          where a=g*alpha, d=1+a, e=2*a*gr   (R_PARAM=0.5 folded in)
//   Mfwd = I + (k/2)A*(2-alpha) = [[1-b,0,0,-eF],[b,1-b,0,0],[0,b,1-b,0],[0,0,b,1-b]]
//          where b=g*(2-alpha), eF=2*b*gr
//   b_a   = a  (component 0 only);  b_1ma = g*(1-alpha/2) = h
// Solve Mlhs*xn = r in closed form (bidiagonal + corner):
//   x0 = (d^3*r0 - e*(d^2*r3 + a*d*r2 + a^2*r1)) / (d^4 + e*a^3)
//   x1 = (r1 + a*x0)/d ; x2 = (r2 + a*x1)/d ; x3 = (r3 + a*x2)/d
//
// out layout: [0,B) y_n | [B,5B) x_n | [5B,6B) u_n copy

__global__ __launch_bounds__(256) void moog_fused(
        const float4* __restrict__ u4,
        const float4* __restrict__ x4,      // one float4 per SAMPLE
        const float4* __restrict__ u14,
        const float*  __restrict__ gf_p,
        const float*  __restrict__ gr_p,
        const float*  __restrict__ gain_p,
        const float*  __restrict__ alpha_p,
        float* __restrict__ out,
        int B) {
    int t = blockIdx.x * blockDim.x + threadIdx.x;   // one thread = 4 samples
    int nq = B >> 2;
    if (t >= nq) return;

    // ---- uniform constants (scalar-cached loads, ~30 VALU ops) ----
    const float k  = 1.0f / 44100.0f;
    const float w  = 2.0f * (float)M_PI * gf_p[0] * 1000.0f;
    const float g  = 0.5f * k * w;
    const float al = alpha_p[0];
    const float grv = gr_p[0];
    const float gn  = gain_p[0];

    const float a = g * al;
    const float d = 1.0f + a;
    const float e = 2.0f * a * grv;
    const float b = g * (2.0f - al);
    const float eF = 2.0f * b * grv;
    const float h = g * (1.0f - 0.5f * al);
    const float omb = 1.0f - b;

    const float invd = 1.0f / d;
    const float d2 = d * d;
    const float d3 = d2 * d;
    const float deninv = 1.0f / (d3 * d + e * a * a * a);
    const float c0 =  d3 * deninv;
    const float c3 = -e * d2 * deninv;
    const float c2 = -e * a * d * deninv;
    const float c1 = -e * a * a * deninv;

    // ---- load 4 samples' worth of u, u1 ----
    float4 u  = u4[t];
    float4 u1 = u14[t];
    const float* up  = (const float*)&u;
    const float* u1p = (const float*)&u1;

    float4* ox = (float4*)(out + (size_t)B);          // x_n block
    float4* oy = (float4*)out;                        // y_n block
    float4* ou = (float4*)(out + 5 * (size_t)B);      // u_n copy block

    float ys[4];
#pragma unroll
    for (int q = 0; q < 4; ++q) {
        float4 x = x4[4 * t + q];
        float uu  = up[q];
        float uu1 = u1p[q];

        float r0 = omb * x.x - eF * x.w + a * uu + h * uu1;
        float r1 = b * x.x + omb * x.y;
        float r2 = b * x.y + omb * x.z;
        float r3 = b * x.z + omb * x.w;

        float X0 = c0 * r0 + c1 * r1 + c2 * r2 + c3 * r3;
        float X1 = (r1 + a * X0) * invd;
        float X2 = (r2 + a * X1) * invd;
        float X3 = (r3 + a * X2) * invd;

        ox[4 * t + q] = make_float4(X0, X1, X2, X3);
        ys[q] = gn * X3;
    }

    oy[t] = make_float4(ys[0], ys[1], ys[2], ys[3]);
    ou[t] = u;
}

extern "C" void kernel_launch(void* const* d_in, const int* in_sizes, int n_in,
                              void* d_out, int out_size, void* d_ws, size_t ws_size,
                              hipStream_t stream) {
    const float* u_n   = (const float*)d_in[0];
    const float* x_n1  = (const float*)d_in[1];
    const float* u_n1  = (const float*)d_in[2];
    const float* gf    = (const float*)d_in[3];
    const float* gr    = (const float*)d_in[4];
    const float* gain  = (const float*)d_in[5];
    const float* alpha = (const float*)d_in[6];

    int B = in_sizes[0];
    int nq = B >> 2;
    int block = 256;
    int grid = (nq + block - 1) / block;

    moog_fused<<<grid, block, 0, stream>>>(
        (const float4*)u_n, (const float4*)x_n1, (const float4*)u_n1,
        gf, gr, gain, alpha, (float*)d_out, B);
}

// Round 3
// 191.824 us; speedup vs baseline: 1.0250x; 1.0250x over previous
//
#include <hip/hip_runtime.h>
#include <math.h>

// MoogVCF RF cell — single fused kernel, lane-major layout.
//
// Algebra (closed-form solve of the bidiagonal+corner system, see R1/R2):
//   a=g*alpha, d=1+a, e=2*a*gr, b=g*(2-alpha), eF=2*b*gr, h=g*(1-alpha/2)
//   r0 = (1-b)x0 - eF*x3 + a*u + h*u1 ; r_i = b*x_{i-1} + (1-b)*x_i
//   X0 = (d^3 r0 - e(a^2 r1 + a d r2 + d^2 r3)) / (d^4 + e a^3)
//   X_i = (r_i + a X_{i-1}) / d
//
// Layout: wave w owns samples [256w, 256w+256); iteration q (0..3) gives
// lane l sample s = 256w + 64q + l  ->  EVERY memory instruction is
// wave-contiguous (x: 1KB/instr, scalars: 256B/instr).
// Outputs via nontemporal stores (never re-read; keep L2/MALL for inputs).
//
// out layout: [0,B) y_n | [B,5B) x_n | [5B,6B) u_n copy

typedef float v4f __attribute__((ext_vector_type(4)));

__global__ __launch_bounds__(256) void moog_fused(
        const float* __restrict__ u_n,
        const v4f*  __restrict__ x4,      // one float4 per sample
        const float* __restrict__ u_n1,
        const float* __restrict__ gf_p,
        const float* __restrict__ gr_p,
        const float* __restrict__ gain_p,
        const float* __restrict__ alpha_p,
        float* __restrict__ out,
        int B) {
    const int tid  = blockIdx.x * 256 + threadIdx.x;
    const int wv   = tid >> 6;            // global wave id
    const int lane = threadIdx.x & 63;
    const size_t sb = (size_t)wv * 256;   // wave's first sample
    if ((int)sb >= B) return;

    // ---- issue all loads first (12 independent chains) ----
    v4f  xs[4];
    float us[4], u1s[4];
#pragma unroll
    for (int q = 0; q < 4; ++q) {
        size_t s = sb + 64 * q + lane;
        xs[q]  = x4[s];
        us[q]  = u_n[s];
        u1s[q] = u_n1[s];
    }

    // ---- uniform constants ----
    const float k   = 1.0f / 44100.0f;
    const float w   = 2.0f * (float)M_PI * gf_p[0] * 1000.0f;
    const float g   = 0.5f * k * w;
    const float al  = alpha_p[0];
    const float grv = gr_p[0];
    const float gn  = gain_p[0];

    const float a   = g * al;
    const float d   = 1.0f + a;
    const float e   = 2.0f * a * grv;
    const float b   = g * (2.0f - al);
    const float eF  = 2.0f * b * grv;
    const float h   = g * (1.0f - 0.5f * al);
    const float omb = 1.0f - b;

    const float invd = 1.0f / d;
    const float d2 = d * d;
    const float d3 = d2 * d;
    const float deninv = 1.0f / (d3 * d + e * a * a * a);
    const float c0 =  d3 * deninv;
    const float c3 = -e * d2 * deninv;
    const float c2 = -e * a * d * deninv;
    const float c1 = -e * a * a * deninv;

    float* oy = out;
    v4f*   ox = (v4f*)(out + (size_t)B);
    float* ou = out + 5 * (size_t)B;

#pragma unroll
    for (int q = 0; q < 4; ++q) {
        size_t s = sb + 64 * q + lane;
        v4f x = xs[q];
        float uu  = us[q];
        float uu1 = u1s[q];

        float r0 = omb * x.x - eF * x.w + a * uu + h * uu1;
        float r1 = b * x.x + omb * x.y;
        float r2 = b * x.y + omb * x.z;
        float r3 = b * x.z + omb * x.w;

        float X0 = c0 * r0 + c1 * r1 + c2 * r2 + c3 * r3;
        float X1 = (r1 + a * X0) * invd;
        float X2 = (r2 + a * X1) * invd;
        float X3 = (r3 + a * X2) * invd;

        v4f xv = {X0, X1, X2, X3};
        __builtin_nontemporal_store(xv, &ox[s]);
        __builtin_nontemporal_store(gn * X3, &oy[s]);
        __builtin_nontemporal_store(uu, &ou[s]);
    }
}

extern "C" void kernel_launch(void* const* d_in, const int* in_sizes, int n_in,
                              void* d_out, int out_size, void* d_ws, size_t ws_size,
                              hipStream_t stream) {
    const float* u_n   = (const float*)d_in[0];
    const float* x_n1  = (const float*)d_in[1];
    const float* u_n1  = (const float*)d_in[2];
    const float* gf    = (const float*)d_in[3];
    const float* gr    = (const float*)d_in[4];
    const float* gain  = (const float*)d_in[5];
    const float* alpha = (const float*)d_in[6];

    int B = in_sizes[0];
    int nthreads = B >> 2;                 // 4 samples per thread
    int block = 256;
    int grid = (nthreads + block - 1) / block;

    moog_fused<<<grid, block, 0, stream>>>(
        u_n, (const v4f*)x_n1, u_n1,
        gf, gr, gain, alpha, (float*)d_out, B);
}